// Round 1
// baseline (124.717 us; speedup 1.0000x reference)
//
#include <hip/hip_runtime.h>
#include <hip/hip_bf16.h>

#define TOKENS 8192
#define D_IN   256
#define HDIM   1024
#define ODIM   768
#define KPACK  1056   // 4*256 data cols + 32 pad block (first 4 = bias coeff)
#define NCAT   1792   // 1024 hid + 768 res

typedef short bf16x8 __attribute__((ext_vector_type(8)));
typedef float f32x4  __attribute__((ext_vector_type(4)));

static __device__ __forceinline__ ushort f2b(float f) {
    union { __hip_bfloat16 b; ushort u; } cv;
    cv.b = __float2bfloat16(f);
    return cv.u;
}

// ---- K0a: per-(expert,token) combine weight --------------------------------
__global__ __launch_bounds__(256) void k_route(
    const float* __restrict__ ew, const int* __restrict__ ei,
    float* __restrict__ wmap) {
    int n = blockIdx.x * 256 + threadIdx.x;
    if (n >= TOKENS) return;
    int   i0 = ei[2 * n], i1 = ei[2 * n + 1];
    float w0 = ew[2 * n], w1 = ew[2 * n + 1];
    bool v0 = (unsigned)i0 < 4u, v1 = (unsigned)i1 < 4u;
    float rs = (v0 ? w0 : 0.f) + (v1 ? w1 : 0.f);
    if (rs == 0.f) rs = 1.f;
    float o0 = v0 ? w0 / rs : 0.f;
    float o1 = v1 ? w1 / rs : 0.f;
#pragma unroll
    for (int e = 0; e < 4; ++e) {
        float m = 0.f;
        if (v0 && i0 == e) m += o0;
        if (v1 && i1 == e) m += o1;
        wmap[e * TOKENS + n] = m;
    }
}

// ---- K0b: pack A'' = wmap-scaled, masked, nan-fixed x_final (bf16) ---------
__global__ __launch_bounds__(256) void k_pack_a(
    const float* __restrict__ xf, const float* __restrict__ wmap,
    ushort* __restrict__ Ap) {
    int gid = blockIdx.x * 256 + threadIdx.x;   // one 8-col item; 8192*132 items
    int n  = gid / 132;
    int c8 = gid - n * 132;
    ushort o[8] __attribute__((aligned(16))) = {0, 0, 0, 0, 0, 0, 0, 0};
    if (c8 < 128) {
        int e  = c8 >> 5;
        int d0 = (c8 & 31) << 3;
        float w = wmap[e * TOKENS + n];
        bool keep = (d0 & 127) < 32 * (e + 1);
        if (w != 0.f && keep) {
            const float* s = xf + ((size_t)e * TOKENS + n) * D_IN + d0;
#pragma unroll
            for (int j = 0; j < 8; ++j) {
                float v = s[j];
                if (!(v == v)) v = 0.f;   // nan_to_num
                o[j] = f2b(w * v);
            }
        }
    } else if (c8 == 128) {
#pragma unroll
        for (int j = 0; j < 4; ++j) o[j] = f2b(wmap[j * TOKENS + n]);
    }
    *(uint4*)(Ap + (size_t)n * KPACK + c8 * 8) = *(const uint4*)o;
}

// ---- K0c: pack B'' = [W_hid;W_res] along K, bias in cols 1024..1027 --------
__global__ __launch_bounds__(256) void k_pack_b(
    const float* __restrict__ Whid, const float* __restrict__ bhid,
    const float* __restrict__ Wres, const float* __restrict__ bres,
    ushort* __restrict__ Bp) {
    int gid = blockIdx.x * 256 + threadIdx.x;   // 1792*132 items
    int o_ = gid / 132;
    int c8 = gid - o_ * 132;
    ushort v[8] __attribute__((aligned(16))) = {0, 0, 0, 0, 0, 0, 0, 0};
    if (c8 < 128) {
        int e  = c8 >> 5;
        int d0 = (c8 & 31) << 3;
        const float* s = (o_ < HDIM)
            ? Whid + ((size_t)e * HDIM + o_) * D_IN + d0
            : Wres + ((size_t)e * ODIM + (o_ - HDIM)) * D_IN + d0;
#pragma unroll
        for (int j = 0; j < 8; ++j) v[j] = f2b(s[j]);
    } else if (c8 == 128) {
#pragma unroll
        for (int j = 0; j < 4; ++j) {
            float b = (o_ < HDIM) ? bhid[j * HDIM + o_] : bres[j * ODIM + (o_ - HDIM)];
            v[j] = f2b(b);
        }
    }
    *(uint4*)(Bp + (size_t)o_ * KPACK + c8 * 8) = *(const uint4*)v;
}

// ---- K0d: W_out f32 -> bf16 -------------------------------------------------
__global__ __launch_bounds__(256) void k_pack_wout(
    const float* __restrict__ Wout, ushort* __restrict__ Wb) {
    int gid = blockIdx.x * 256 + threadIdx.x;   // 768*1024/8 items
    const float* s = Wout + (size_t)gid * 8;
    ushort v[8] __attribute__((aligned(16)));
#pragma unroll
    for (int j = 0; j < 8; ++j) v[j] = f2b(s[j]);
    *(uint4*)(Wb + (size_t)gid * 8) = *(const uint4*)v;
}

// ---- GEMM1: (8192 x 1792) = A''(8192x1056) @ B''^T; epilogue GELU/split ----
__global__ __launch_bounds__(256) void k_gemm1(
    const ushort* __restrict__ A, const ushort* __restrict__ B,
    ushort* __restrict__ hidB, float* __restrict__ outpre) {
    __shared__ __align__(16) ushort As[128][40];
    __shared__ __align__(16) ushort Bs[128][40];
    const int tid = threadIdx.x;
    const int lane = tid & 63;
    const int w = tid >> 6;
    const int wm = (w >> 1) * 64, wn = (w & 1) * 64;
    const int bm = blockIdx.x, bn = blockIdx.y;
    const int ar = tid >> 2, ac = (tid & 3) * 8;
    const ushort* Ag = A + (size_t)(bm * 128 + ar) * KPACK + ac;
    const ushort* Bg = B + (size_t)(bn * 128 + ar) * KPACK + ac;
    const int r = lane & 15, g = lane >> 4;
    f32x4 acc[4][4] = {};
    for (int kt = 0; kt < KPACK; kt += 32) {
        uint4 a0 = *(const uint4*)(Ag + kt);
        uint4 a1 = *(const uint4*)(Ag + (size_t)64 * KPACK + kt);
        uint4 b0 = *(const uint4*)(Bg + kt);
        uint4 b1 = *(const uint4*)(Bg + (size_t)64 * KPACK + kt);
        __syncthreads();
        *(uint4*)&As[ar][ac] = a0;
        *(uint4*)&As[ar + 64][ac] = a1;
        *(uint4*)&Bs[ar][ac] = b0;
        *(uint4*)&Bs[ar + 64][ac] = b1;
        __syncthreads();
        bf16x8 af[4], bfr[4];
#pragma unroll
        for (int i = 0; i < 4; ++i)
            af[i] = *(const bf16x8*)&As[wm + i * 16 + r][g * 8];
#pragma unroll
        for (int j = 0; j < 4; ++j)
            bfr[j] = *(const bf16x8*)&Bs[wn + j * 16 + r][g * 8];
#pragma unroll
        for (int i = 0; i < 4; ++i)
#pragma unroll
            for (int j = 0; j < 4; ++j)
                acc[i][j] = __builtin_amdgcn_mfma_f32_16x16x32_bf16(
                    af[i], bfr[j], acc[i][j], 0, 0, 0);
    }
#pragma unroll
    for (int i = 0; i < 4; ++i) {
#pragma unroll
        for (int j = 0; j < 4; ++j) {
            int col = bn * 128 + wn + j * 16 + r;
#pragma unroll
            for (int q = 0; q < 4; ++q) {
                int row = bm * 128 + wm + i * 16 + g * 4 + q;
                float v = acc[i][j][q];
                if (col < HDIM) {
                    float ge = 0.5f * v * (1.f + erff(v * 0.70710678f));
                    hidB[(size_t)row * HDIM + col] = f2b(ge);
                } else {
                    outpre[(size_t)row * ODIM + (col - HDIM)] = v;
                }
            }
        }
    }
}

// ---- GEMM2: out = hid @ W_out^T + b_out + res (in-place on outpre) ---------
__global__ __launch_bounds__(256) void k_gemm2(
    const ushort* __restrict__ A, const ushort* __restrict__ B,
    const float* __restrict__ bout, float* __restrict__ outpre) {
    __shared__ __align__(16) ushort As[128][40];
    __shared__ __align__(16) ushort Bs[128][40];
    const int tid = threadIdx.x;
    const int lane = tid & 63;
    const int w = tid >> 6;
    const int wm = (w >> 1) * 64, wn = (w & 1) * 64;
    const int bm = blockIdx.x, bn = blockIdx.y;
    const int ar = tid >> 2, ac = (tid & 3) * 8;
    const ushort* Ag = A + (size_t)(bm * 128 + ar) * HDIM + ac;
    const ushort* Bg = B + (size_t)(bn * 128 + ar) * HDIM + ac;
    const int r = lane & 15, g = lane >> 4;
    f32x4 acc[4][4] = {};
    for (int kt = 0; kt < HDIM; kt += 32) {
        uint4 a0 = *(const uint4*)(Ag + kt);
        uint4 a1 = *(const uint4*)(Ag + (size_t)64 * HDIM + kt);
        uint4 b0 = *(const uint4*)(Bg + kt);
        uint4 b1 = *(const uint4*)(Bg + (size_t)64 * HDIM + kt);
        __syncthreads();
        *(uint4*)&As[ar][ac] = a0;
        *(uint4*)&As[ar + 64][ac] = a1;
        *(uint4*)&Bs[ar][ac] = b0;
        *(uint4*)&Bs[ar + 64][ac] = b1;
        __syncthreads();
        bf16x8 af[4], bfr[4];
#pragma unroll
        for (int i = 0; i < 4; ++i)
            af[i] = *(const bf16x8*)&As[wm + i * 16 + r][g * 8];
#pragma unroll
        for (int j = 0; j < 4; ++j)
            bfr[j] = *(const bf16x8*)&Bs[wn + j * 16 + r][g * 8];
#pragma unroll
        for (int i = 0; i < 4; ++i)
#pragma unroll
            for (int j = 0; j < 4; ++j)
                acc[i][j] = __builtin_amdgcn_mfma_f32_16x16x32_bf16(
                    af[i], bfr[j], acc[i][j], 0, 0, 0);
    }
#pragma unroll
    for (int i = 0; i < 4; ++i) {
#pragma unroll
        for (int j = 0; j < 4; ++j) {
            int col = bn * 128 + wn + j * 16 + r;
#pragma unroll
            for (int q = 0; q < 4; ++q) {
                int row = bm * 128 + wm + i * 16 + g * 4 + q;
                size_t idx = (size_t)row * ODIM + col;
                outpre[idx] = acc[i][j][q] + bout[col] + outpre[idx];
            }
        }
    }
}

// ---- RMS norm row-wise ------------------------------------------------------
__global__ __launch_bounds__(256) void k_rms(
    const float* __restrict__ outpre, const float* __restrict__ lnw,
    float* __restrict__ out) {
    int row = blockIdx.x, t = threadIdx.x;
    const float* p = outpre + (size_t)row * ODIM;
    float v0 = p[t], v1 = p[t + 256], v2 = p[t + 512];
    float s = v0 * v0 + v1 * v1 + v2 * v2;
#pragma unroll
    for (int off = 32; off > 0; off >>= 1) s += __shfl_down(s, off, 64);
    __shared__ float ws4[4];
    if ((t & 63) == 0) ws4[t >> 6] = s;
    __syncthreads();
    float tot = ws4[0] + ws4[1] + ws4[2] + ws4[3];
    float sc = rsqrtf(tot * (1.f / 768.f) + 1e-6f);
    out[(size_t)row * ODIM + t]       = lnw[t]       * v0 * sc;
    out[(size_t)row * ODIM + t + 256] = lnw[t + 256] * v1 * sc;
    out[(size_t)row * ODIM + t + 512] = lnw[t + 512] * v2 * sc;
}

extern "C" void kernel_launch(void* const* d_in, const int* in_sizes, int n_in,
                              void* d_out, int out_size, void* d_ws, size_t ws_size,
                              hipStream_t stream) {
    const float* ew   = (const float*)d_in[2];
    const int*   ei   = (const int*)d_in[3];
    const float* xf   = (const float*)d_in[4];
    const float* Whid = (const float*)d_in[5];
    const float* bhid = (const float*)d_in[6];
    const float* Wout = (const float*)d_in[7];
    const float* bout = (const float*)d_in[8];
    const float* Wres = (const float*)d_in[9];
    const float* bres = (const float*)d_in[10];
    const float* lnw  = (const float*)d_in[11];

    char* ws = (char*)d_ws;
    float*  wmap   = (float*)(ws);                   // 4*8192*4      = 131072
    ushort* Ap     = (ushort*)(ws + 131072);         // 8192*1056*2   = 17301504
    ushort* Bp     = (ushort*)(ws + 17432576);       // 1792*1056*2   = 3784704
    ushort* Wb     = (ushort*)(ws + 21217280);       // 768*1024*2    = 1572864
    ushort* hidB   = (ushort*)(ws + 22790144);       // 8192*1024*2   = 16777216
    float*  outpre = (float*)(ws + 39567360);        // 8192*768*4    = 25165824
                                                     // total ~64.7 MB

    k_route<<<32, 256, 0, stream>>>(ew, ei, wmap);
    k_pack_a<<<4224, 256, 0, stream>>>(xf, wmap, Ap);
    k_pack_b<<<924, 256, 0, stream>>>(Whid, bhid, Wres, bres, Bp);
    k_pack_wout<<<384, 256, 0, stream>>>(Wout, Wb);
    k_gemm1<<<dim3(64, 14), 256, 0, stream>>>(Ap, Bp, hidB, outpre);
    k_gemm2<<<dim3(64, 6), 256, 0, stream>>>(hidB, Wb, bout, outpre);
    k_rms<<<8192, 256, 0, stream>>>(outpre, lnw, (float*)d_out);
}